// Round 13
// baseline (84.283 us; speedup 1.0000x reference)
//
#include <hip/hip_runtime.h>

#define NPTS  4096
#define KNN   16
#define K1    17            // KNN + self
#define NBLK  64            // candidate blocks per batch == wave width
#define CELLS 4096          // 16^3 Morton cells
#define EPSF  1e-10f

__device__ __forceinline__ unsigned umin_(unsigned a, unsigned b) { return a < b ? a : b; }
__device__ __forceinline__ unsigned umax_(unsigned a, unsigned b) { return a < b ? b : a; }
__device__ __forceinline__ unsigned rdlane(unsigned v, int l) {
    return (unsigned)__builtin_amdgcn_readlane((int)v, l);
}

// cheap cross-lane primitives (DPP = VALU, ds_swizzle = DS pipe, shfl = ds_permute)
#define DPP_XOR1(v)  ((unsigned)__builtin_amdgcn_update_dpp(0, (int)(v), 0xB1, 0xF, 0xF, true))
#define DPP_XOR2(v)  ((unsigned)__builtin_amdgcn_update_dpp(0, (int)(v), 0x4E, 0xF, 0xF, true))
#define SWZ_XOR(v,J) ((unsigned)__builtin_amdgcn_ds_swizzle((int)(v), ((J) << 10) | 0x1F))
#define DPP_SHR1(v)  ((unsigned)__builtin_amdgcn_update_dpp(0, (int)(v), 0x111, 0xF, 0xF, true))
#define DPPF_SHR(vf, CTRL) __uint_as_float((unsigned)__builtin_amdgcn_update_dpp(0, (int)__float_as_uint(vf), CTRL, 0xF, 0xF, true))
#define LXOR1(v)  DPP_XOR1(v)
#define LXOR2(v)  DPP_XOR2(v)
#define LXOR4(v)  SWZ_XOR(v, 4)
#define LXOR8(v)  SWZ_XOR(v, 8)
#define LXOR16(v) SWZ_XOR(v, 16)
#define LXOR32(v) ((unsigned)__shfl_xor((int)(v), 32))

// one compare-exchange stage applied to FOUR sort chains (2 queries x 2 arrays)
#define BSTEP4(K, XORF) do {                                                  \
    unsigned oa0_ = XORF(arr0), ob0_ = XORF(bk0);                             \
    unsigned oa1_ = XORF(arr1), ob1_ = XORF(bk1);                             \
    bool tm_ = (((lane & (J_)) == 0) == ((lane & (K)) == 0));                 \
    unsigned mna0_ = umin_(arr0, oa0_), mxa0_ = umax_(arr0, oa0_);            \
    unsigned mnb0_ = umin_(bk0,  ob0_), mxb0_ = umax_(bk0,  ob0_);            \
    unsigned mna1_ = umin_(arr1, oa1_), mxa1_ = umax_(arr1, oa1_);            \
    unsigned mnb1_ = umin_(bk1,  ob1_), mxb1_ = umax_(bk1,  ob1_);            \
    arr0 = tm_ ? mna0_ : mxa0_; bk0 = tm_ ? mnb0_ : mxb0_;                    \
    arr1 = tm_ ? mna1_ : mxa1_; bk1 = tm_ ? mnb1_ : mxb1_;                    \
} while (0)

// one event pop: broadcast key from lane l_, ballot-position insert (self-
// correcting: key >= current arr[16] lands at pos >= 17 = garbage lanes)
#define EV_BODY(KEY, ARR, MM) do {                                            \
    int l_ = __ffsll(MM) - 1;                                                 \
    MM &= MM - 1;                                                             \
    unsigned kk_ = rdlane(KEY, l_);                                           \
    unsigned long long lt_ = __ballot(ARR < kk_) & 0x1FFFFull;                \
    int pos_ = __popcll(lt_);                                                 \
    unsigned up_ = DPP_SHR1(ARR);                                             \
    unsigned a15_ = rdlane(ARR, 15);                                          \
    up_ = (lane == 16) ? a15_ : up_;                                          \
    ARR = (lane == pos_) ? kk_ : ((lane > pos_) ? up_ : ARR);                 \
} while (0)

// spread 4 bits to positions 0,3,6,9
__device__ __forceinline__ unsigned sp4(int v) {
    unsigned x = (unsigned)v;
    return (x & 1u) | ((x & 2u) << 2) | ((x & 4u) << 4) | ((x & 8u) << 6);
}

// ---- Kernel 1: per-batch counting sort by 12-bit Morton cell + per-64-block
// bboxes. Sort is permutation-only (exactness never depends on it); bboxes
// are true min/max of actual points.
__global__ __launch_bounds__(1024) void sort_kernel(
    const float* __restrict__ pref,
    float4* __restrict__ wxyzw, int* __restrict__ widx, float4* __restrict__ wbb)
{
    __shared__ unsigned hist[CELLS];          // 16 KB
    __shared__ unsigned short cells[NPTS];    // 8 KB
    __shared__ unsigned wofs[16];
    const int tid  = threadIdx.x;
    const int lane = tid & 63, w = tid >> 6;
    const int b = blockIdx.x;
    const float* prb = pref + (size_t)b * NPTS * 3;
    const size_t base = (size_t)b * NPTS;

    for (int t = tid; t < CELLS; t += 1024) hist[t] = 0u;
    __syncthreads();

    for (int p = tid; p < NPTS; p += 1024) {
        float x = prb[3 * p + 0], y = prb[3 * p + 1], z = prb[3 * p + 2];
        int cx = min(15, max(0, (int)((x + 4.0f) * 2.0f)));
        int cy = min(15, max(0, (int)((y + 4.0f) * 2.0f)));
        int cz = min(15, max(0, (int)((z + 4.0f) * 2.0f)));
        unsigned m = sp4(cx) | (sp4(cy) << 1) | (sp4(cz) << 2);
        cells[p] = (unsigned short)m;
        atomicAdd(&hist[m], 1u);
    }
    __syncthreads();

    // Exclusive scan of hist[4096]; thread t owns cells 4t..4t+3.
    unsigned l0 = hist[4 * tid + 0], l1 = hist[4 * tid + 1];
    unsigned l2 = hist[4 * tid + 2], l3 = hist[4 * tid + 3];
    unsigned s = l0 + l1 + l2 + l3;
    unsigned run = s;
#pragma unroll
    for (int d = 1; d < 64; d <<= 1) {
        unsigned o = __shfl_up(run, d);
        if (lane >= d) run += o;
    }
    if (lane == 63) wofs[w] = run;
    __syncthreads();
    if (tid == 0) {
        unsigned acc = 0;
#pragma unroll
        for (int k = 0; k < 16; ++k) { unsigned t2 = wofs[k]; wofs[k] = acc; acc += t2; }
    }
    __syncthreads();
    unsigned excl = wofs[w] + run - s;
    hist[4 * tid + 0] = excl;
    hist[4 * tid + 1] = excl + l0;
    hist[4 * tid + 2] = excl + l0 + l1;
    hist[4 * tid + 3] = excl + l0 + l1 + l2;
    __syncthreads();

    for (int p = tid; p < NPTS; p += 1024) {
        unsigned c = cells[p];
        unsigned pos = atomicAdd(&hist[c], 1u);
        wxyzw[base + pos] = make_float4(prb[3 * p + 0], prb[3 * p + 1], prb[3 * p + 2], 0.f);
        widx[base + pos]  = p;
    }
    __syncthreads();

    // Per-block bboxes: wave w handles blocks w, w+16, w+32, w+48.
#pragma unroll
    for (int rep = 0; rep < 4; ++rep) {
        int blk = w + rep * 16;
        float4 c = wxyzw[base + blk * 64 + lane];
        float mnx = c.x, mxx = c.x, mny = c.y, mxy2 = c.y, mnz = c.z, mxz = c.z;
#pragma unroll
        for (int d = 32; d > 0; d >>= 1) {
            mnx  = fminf(mnx,  __shfl_xor(mnx,  d));
            mxx  = fmaxf(mxx,  __shfl_xor(mxx,  d));
            mny  = fminf(mny,  __shfl_xor(mny,  d));
            mxy2 = fmaxf(mxy2, __shfl_xor(mxy2, d));
            mnz  = fminf(mnz,  __shfl_xor(mnz,  d));
            mxz  = fmaxf(mxz,  __shfl_xor(mxz,  d));
        }
        if (lane == 0) {
            wbb[((size_t)b * NBLK + blk) * 2 + 0] = make_float4(mnx, mny, mnz, 0.f);
            wbb[((size_t)b * NBLK + blk) * 2 + 1] = make_float4(mxx, mxy2, mxz, 0.f);
        }
    }
}

// ---- Kernel 2: TWO hash-permuted queries per wave, processed concurrently
// (ILP hides the serial cross-lane/DS chains); distance-ordered bbox walk
// with early exit; exact top-17; batch-stale threshold (exact, see EV_BODY).
__global__ __launch_bounds__(128, 8) void knn_main_kernel(
    const float* __restrict__ ppred,
    const float4* __restrict__ wxyzw, const int* __restrict__ widx,
    const float4* __restrict__ wbb, float* __restrict__ partials, int NQ)
{
    const int lane = threadIdx.x & 63;
    const int wv   = blockIdx.x * 2 + (threadIdx.x >> 6);
    const bool pow2 = (NQ & (NQ - 1)) == 0;
    const int qid0 = wv * 2, qid1 = wv * 2 + 1;
    const int q0 = pow2 ? (int)(((unsigned)qid0 * 26765u) & (unsigned)(NQ - 1)) : qid0;
    const int q1 = pow2 ? (int)(((unsigned)qid1 * 26765u) & (unsigned)(NQ - 1)) : qid1;

    const int b0 = q0 >> 12, b1 = q1 >> 12;
    const int p0 = q0 & (NPTS - 1), p1 = q1 & (NPTS - 1);
    const size_t base0 = (size_t)b0 * NPTS, base1 = (size_t)b1 * NPTS;
    const int pb0 = p0 & ~63, pb1 = p1 & ~63;
    const int ownblk0 = p0 >> 6, ownblk1 = p1 >> 6;

    const float4 qc0 = wxyzw[base0 + p0];
    const float4 qc1 = wxyzw[base1 + p1];
    const float qx0 = qc0.x, qy0 = qc0.y, qz0 = qc0.z;
    const float qx1 = qc1.x, qy1 = qc1.y, qz1 = qc1.z;

    // own-block candidate keys (self d2 == +0.0 -> key = p = minimum)
    unsigned arr0, arr1;
    {
        float4 c0 = wxyzw[base0 + pb0 + lane];
        float4 c1 = wxyzw[base1 + pb1 + lane];
        float dx0 = c0.x - qx0, dy0 = c0.y - qy0, dz0 = c0.z - qz0;
        float dx1 = c1.x - qx1, dy1 = c1.y - qy1, dz1 = c1.z - qz1;
        float d20 = dx0 * dx0 + dy0 * dy0 + dz0 * dz0;
        float d21 = dx1 * dx1 + dy1 * dy1 + dz1 * dz1;
        arr0 = (__float_as_uint(d20) & 0xFFFFF000u) | (unsigned)(pb0 + lane);
        arr1 = (__float_as_uint(d21) & 0xFFFFF000u) | (unsigned)(pb1 + lane);
    }
    // bbox lower-bound keys (trunc same as real keys; blk index <= any j)
    unsigned bk0, bk1;
    {
        float4 mn0 = wbb[((size_t)b0 * NBLK + lane) * 2 + 0];
        float4 mx0 = wbb[((size_t)b0 * NBLK + lane) * 2 + 1];
        float4 mn1 = wbb[((size_t)b1 * NBLK + lane) * 2 + 0];
        float4 mx1 = wbb[((size_t)b1 * NBLK + lane) * 2 + 1];
        float dx0 = fmaxf(fmaxf(mn0.x - qx0, qx0 - mx0.x), 0.0f);
        float dy0 = fmaxf(fmaxf(mn0.y - qy0, qy0 - mx0.y), 0.0f);
        float dz0 = fmaxf(fmaxf(mn0.z - qz0, qz0 - mx0.z), 0.0f);
        float dx1 = fmaxf(fmaxf(mn1.x - qx1, qx1 - mx1.x), 0.0f);
        float dy1 = fmaxf(fmaxf(mn1.y - qy1, qy1 - mx1.y), 0.0f);
        float dz1 = fmaxf(fmaxf(mn1.z - qz1, qz1 - mx1.z), 0.0f);
        float bd0 = dx0 * dx0 + dy0 * dy0 + dz0 * dz0;
        float bd1 = dx1 * dx1 + dy1 * dy1 + dz1 * dz1;
        bk0 = (__float_as_uint(bd0) & 0xFFFFF000u) | (unsigned)lane;
        bk1 = (__float_as_uint(bd1) & 0xFFFFF000u) | (unsigned)lane;
        bk0 = (lane == ownblk0) ? 0xFFFFFFFFu : bk0;
        bk1 = (lane == ownblk1) ? 0xFFFFFFFFu : bk1;
    }

    // joint bitonic sort of 4 chains (ascending) through one network
    {
        int J_;
        J_ = 1;  BSTEP4(2,  LXOR1);
        J_ = 2;  BSTEP4(4,  LXOR2);  J_ = 1; BSTEP4(4,  LXOR1);
        J_ = 4;  BSTEP4(8,  LXOR4);  J_ = 2; BSTEP4(8,  LXOR2);  J_ = 1; BSTEP4(8,  LXOR1);
        J_ = 8;  BSTEP4(16, LXOR8);  J_ = 4; BSTEP4(16, LXOR4);  J_ = 2; BSTEP4(16, LXOR2);  J_ = 1; BSTEP4(16, LXOR1);
        J_ = 16; BSTEP4(32, LXOR16); J_ = 8; BSTEP4(32, LXOR8);  J_ = 4; BSTEP4(32, LXOR4);  J_ = 2; BSTEP4(32, LXOR2); J_ = 1; BSTEP4(32, LXOR1);
        J_ = 32; BSTEP4(64, LXOR32); J_ = 16; BSTEP4(64, LXOR16); J_ = 8; BSTEP4(64, LXOR8); J_ = 4; BSTEP4(64, LXOR4); J_ = 2; BSTEP4(64, LXOR2); J_ = 1; BSTEP4(64, LXOR1);
    }
    unsigned thr0 = rdlane(arr0, K1 - 1);
    unsigned thr1 = rdlane(arr1, K1 - 1);

    // dual ordered walk: per-query uniform guards, interleaved event loops
    int k0 = 0, k1 = 0;
    unsigned bcur0 = rdlane(bk0, 0), bcur1 = rdlane(bk1, 0);
    bool have0 = (bcur0 < thr0), have1 = (bcur1 < thr1);
    float4 cur0, cur1;
    if (have0) cur0 = wxyzw[base0 + (int)(bcur0 & 0xFFFu) * 64 + lane];
    if (have1) cur1 = wxyzw[base1 + (int)(bcur1 & 0xFFFu) * 64 + lane];

    while (have0 || have1) {
        unsigned long long m0 = 0, m1 = 0;
        unsigned key0 = 0, key1 = 0, bnext0 = 0, bnext1 = 0;
        float4 nxt0, nxt1;
        bool pf0 = false, pf1 = false;
        if (have0) {
            bnext0 = rdlane(bk0, k0 + 1);
            pf0 = (bnext0 < thr0);
            if (pf0) nxt0 = wxyzw[base0 + (int)(bnext0 & 0xFFFu) * 64 + lane];
            float dx = cur0.x - qx0, dy = cur0.y - qy0, dz = cur0.z - qz0;
            float d2 = dx * dx + dy * dy + dz * dz;
            key0 = (__float_as_uint(d2) & 0xFFFFF000u) | (unsigned)((int)(bcur0 & 0xFFFu) * 64 + lane);
            m0 = __ballot(key0 < thr0);
        }
        if (have1) {
            bnext1 = rdlane(bk1, k1 + 1);
            pf1 = (bnext1 < thr1);
            if (pf1) nxt1 = wxyzw[base1 + (int)(bnext1 & 0xFFFu) * 64 + lane];
            float dx = cur1.x - qx1, dy = cur1.y - qy1, dz = cur1.z - qz1;
            float d2 = dx * dx + dy * dy + dz * dz;
            key1 = (__float_as_uint(d2) & 0xFFFFF000u) | (unsigned)((int)(bcur1 & 0xFFFu) * 64 + lane);
            m1 = __ballot(key1 < thr1);
        }
        while (m0 | m1) {                      // two independent chains, ILP
            if (m0) EV_BODY(key0, arr0, m0);
            if (m1) EV_BODY(key1, arr1, m1);
        }
        if (have0) {
            thr0 = rdlane(arr0, K1 - 1);       // refresh once per block
            ++k0; bcur0 = bnext0;
            have0 = (bcur0 < thr0);            // !pf0 => bnext0 >= stale >= new thr
            cur0 = nxt0;
        }
        if (have1) {
            thr1 = rdlane(arr1, K1 - 1);
            ++k1; bcur1 = bnext1;
            have1 = (bcur1 < thr1);
            cur1 = nxt1;
        }
    }

    // Epilogue x2: lanes 1..16 hold the 16 nearest (lane 0 = self).
    {
        const float* ppb = ppred + (size_t)b0 * NPTS * 3;
        const int iorig = widx[base0 + p0];
        float s = 0.f;
        if (lane >= 1 && lane <= KNN) {
            int js = (int)(arr0 & 0xFFFu);
            float4 rc = wxyzw[base0 + js];
            float rx = rc.x - qx0, ry = rc.y - qy0, rz = rc.z - qz0;
            float dref = sqrtf(rx * rx + ry * ry + rz * rz);
            int nj = widx[base0 + js];
            float px = ppb[3 * iorig + 0], py = ppb[3 * iorig + 1], pz = ppb[3 * iorig + 2];
            float ax = ppb[3 * nj + 0] - px;
            float ay = ppb[3 * nj + 1] - py;
            float az = ppb[3 * nj + 2] - pz;
            float dpred = sqrtf(ax * ax + ay * ay + az * az);
            s = fmaxf(dpred / (dref + EPSF) - 1.0f, 0.0f);
        }
        s += DPPF_SHR(s, 0x111);
        s += DPPF_SHR(s, 0x112);
        s += DPPF_SHR(s, 0x114);
        s += DPPF_SHR(s, 0x118);
        float t15 = __uint_as_float(rdlane(__float_as_uint(s), 15));
        float t16 = __uint_as_float(rdlane(__float_as_uint(s), 16));
        if (lane == 0) partials[q0] = t15 + t16;
    }
    {
        const float* ppb = ppred + (size_t)b1 * NPTS * 3;
        const int iorig = widx[base1 + p1];
        float s = 0.f;
        if (lane >= 1 && lane <= KNN) {
            int js = (int)(arr1 & 0xFFFu);
            float4 rc = wxyzw[base1 + js];
            float rx = rc.x - qx1, ry = rc.y - qy1, rz = rc.z - qz1;
            float dref = sqrtf(rx * rx + ry * ry + rz * rz);
            int nj = widx[base1 + js];
            float px = ppb[3 * iorig + 0], py = ppb[3 * iorig + 1], pz = ppb[3 * iorig + 2];
            float ax = ppb[3 * nj + 0] - px;
            float ay = ppb[3 * nj + 1] - py;
            float az = ppb[3 * nj + 2] - pz;
            float dpred = sqrtf(ax * ax + ay * ay + az * az);
            s = fmaxf(dpred / (dref + EPSF) - 1.0f, 0.0f);
        }
        s += DPPF_SHR(s, 0x111);
        s += DPPF_SHR(s, 0x112);
        s += DPPF_SHR(s, 0x114);
        s += DPPF_SHR(s, 0x118);
        float t15 = __uint_as_float(rdlane(__float_as_uint(s), 15));
        float t16 = __uint_as_float(rdlane(__float_as_uint(s), 16));
        if (lane == 0) partials[q1] = t15 + t16;
    }
}

// ---- Kernel 3: deterministic single-block final reduction.
__global__ __launch_bounds__(1024) void reduce_kernel(
    const float* __restrict__ partials, int n, float* __restrict__ out, float scale)
{
    __shared__ float wsum[16];
    float s = 0.f;
    for (int idx = threadIdx.x; idx < n; idx += 1024) s += partials[idx];
    for (int off = 32; off > 0; off >>= 1) s += __shfl_down(s, off);
    if ((threadIdx.x & 63) == 0) wsum[threadIdx.x >> 6] = s;
    __syncthreads();
    if (threadIdx.x == 0) {
        float t = 0.f;
#pragma unroll
        for (int k = 0; k < 16; ++k) t += wsum[k];
        out[0] = t * scale;
    }
}

extern "C" void kernel_launch(void* const* d_in, const int* in_sizes, int n_in,
                              void* d_out, int out_size, void* d_ws, size_t ws_size,
                              hipStream_t stream) {
    const float* pref  = (const float*)d_in[0];
    const float* ppred = (const float*)d_in[1];
    float* out = (float*)d_out;

    const int B  = in_sizes[0] / (NPTS * 3);
    const int NQ = B * NPTS;
    const float scale = 1.0f / ((float)NQ * (float)KNN);

    char* ws = (char*)d_ws;
    float4* wxyzw = (float4*)ws;                                   // B*N*16
    int*    widx  = (int*)   (ws + (size_t)B * NPTS * 16);         // B*N*4
    float4* wbb   = (float4*)(ws + (size_t)B * NPTS * 20);         // B*64*2*16
    float*  partials = (float*)(ws + (size_t)B * NPTS * 20 + (size_t)B * NBLK * 32);

    sort_kernel<<<dim3(B), dim3(1024), 0, stream>>>(pref, wxyzw, widx, wbb);
    knn_main_kernel<<<dim3(NQ / 4), dim3(128), 0, stream>>>(ppred, wxyzw, widx, wbb, partials, NQ);
    reduce_kernel<<<dim3(1), dim3(1024), 0, stream>>>(partials, NQ, out, scale);
}